// Round 6
// baseline (5631.527 us; speedup 1.0000x reference)
//
#include <hip/hip_runtime.h>
#include <hip/hip_bf16.h>

#define TT 1000
#define HH 512
#define HH2 1024
#define DT_ 0.01f
// sqrt(2*DT*SIGMA_RECUR^2), sqrt(2*DT*SIGMA_INPUT^2)
#define PH_SCALE 7.0710678118654745e-4f
#define PI_SCALE 7.0710678118654745e-3f

typedef short s16x8 __attribute__((ext_vector_type(8)));
typedef float f32x4 __attribute__((ext_vector_type(4)));
typedef unsigned long long u64;

#define SIGN64 0x8000800080008000ull
#define STRIP64 0x7fff7fff7fff7fffull

static __device__ __forceinline__ unsigned short bf16_bits(float f) {
    union { __hip_bfloat16 h; unsigned short u; } b; b.h = __float2bfloat16(f); return b.u;
}
// generation tag for h[t]: 2 bits, period 4; same-slot reuse distance 2 -> always differs.
// end-of-run slots hold tags 3/3 and first-run poison 0xAAAA is tag 3, while t=0/1 expect 0.
static __device__ __forceinline__ unsigned pat32(int t) {
    const unsigned tg = ((unsigned)t >> 1) & 3u;
    return ((tg & 1u) << 15) | ((tg & 2u) << 30);
}

// Persistent RNN. Grid: 256 blocks x 64 threads (one wave per block, NO intra-block
// sync, no LDS). Block b: group g=b>>6 (batch rows 16g..16g+16), column slice q=b&63
// (cols q*16..q*16+16). All h exchange through agent-scope relaxed atomics (L3, the
// R3-proven primitive) with generation tags embedded in the sign bits of h (h>=0).
// Publish = 4 relaxed stores, nothing else; consumers poll the data itself. No
// barriers, no fences, no tag array, no vmcnt on the critical path. Deadlock-free:
// a wave only waits for data that its producers will unconditionally publish.
__global__ __launch_bounds__(64, 1) void rnn_persistent(
    const float* __restrict__ inp, const float* __restrict__ hn,
    const float* __restrict__ x0g, const float* __restrict__ inhib,
    const float* __restrict__ ph, const float* __restrict__ pig,
    const float* __restrict__ s2s, const float* __restrict__ a2a,
    const float* __restrict__ a2s, const float* __restrict__ s2a,
    const float* __restrict__ iw,
    float* __restrict__ rnn_out, float* __restrict__ x_out,
    unsigned* __restrict__ hbuf)         // [2][64][512] u32 (packed bf16 pairs)
{
    const int lane = threadIdx.x;        // single wave
    const int b    = blockIdx.x;         // 0..255
    const int g    = b >> 6;             // row group (batch rows 16g..16g+16)
    const int q    = b & 63;             // column slice
    const int l15  = lane & 15;
    const int lq   = lane >> 4;
    const int g16  = g * 16;
    const int icol = q * 16 + l15;       // output column (= W row)
    const int arow = g16 + l15;          // A-fragment row for MFMA loads

    // ---- publish h0 FIRST (cheap; lets every peer's t=0 poll succeed early) ----
    {
        float h0v[4];
        #pragma unroll
        for (int r = 0; r < 4; ++r)
            h0v[r] = hn[(size_t)(g16 + lq * 4 + r) * HH2 + icol];
        float prr[4];
        #pragma unroll
        for (int r = 0; r < 4; ++r) prr[r] = __shfl_xor(h0v[r], 1);
        if (!(l15 & 1)) {
            #pragma unroll
            for (int r = 0; r < 4; ++r) {
                const unsigned val = (((unsigned)bf16_bits(h0v[r]) |
                                       ((unsigned)bf16_bits(prr[r]) << 16)) & 0x7fff7fffu);
                __hip_atomic_store(hbuf + (size_t)(g16 + lq * 4 + r) * 512 + (icol >> 1),
                                   val | pat32(0), __ATOMIC_RELAXED, __HIP_MEMORY_SCOPE_AGENT);
            }
        }
    }

    // ---- W fragments in registers (one-time, f32 -> bf16) ----
    s16x8 wfr[32];
    #pragma unroll
    for (int kc = 0; kc < 32; ++kc) {
        const int j = kc * 32 + lq * 8;
        const float* src;
        if (icol < HH) src = (j < HH) ? (s2s + (size_t)icol * HH + j)
                                      : (a2s + (size_t)icol * HH + (j - HH));
        else           src = (j < HH) ? (s2a + (size_t)(icol - HH) * HH + j)
                                      : (a2a + (size_t)(icol - HH) * HH + (j - HH));
        const float4 f0 = *(const float4*)(src);
        const float4 f1 = *(const float4*)(src + 4);
        union { s16x8 vv; unsigned short us[8]; } u;
        u.us[0] = bf16_bits(f0.x); u.us[1] = bf16_bits(f0.y);
        u.us[2] = bf16_bits(f0.z); u.us[3] = bf16_bits(f0.w);
        u.us[4] = bf16_bits(f1.x); u.us[5] = bf16_bits(f1.y);
        u.us[6] = bf16_bits(f1.z); u.us[7] = bf16_bits(f1.w);
        wfr[kc] = u.vv;
    }

    // ---- register-resident epilogue state ----
    const bool isStr = (icol < HH);
    float iw0 = 0.f, iw1 = 0.f, iw2 = 0.f, iw3 = 0.f;
    if (isStr) {
        iw0 = iw[icol]; iw1 = iw[HH2 + icol];
        iw2 = iw[2 * HH2 + icol]; iw3 = iw[3 * HH2 + icol];
    }
    float xr[4], inh[4];
    float4 ipf[4];
    #pragma unroll
    for (int r = 0; r < 4; ++r) {
        const int bi = g16 + lq * 4 + r;
        xr[r]  = x0g[(size_t)bi * HH2 + icol];
        inh[r] = inhib[(size_t)bi * HH2 + icol];
        ipf[r] = *(const float4*)(inp + ((size_t)bi * TT + 0) * 4);
    }
    float phv = ph[0], piv = pig[0];

    #pragma unroll 1
    for (int t = 0; t < TT; ++t) {
        // slot for h[t] is t&1; each chunk kc is 16B = 2 u64 of packed tagged bf16
        const u64* cur = (const u64*)hbuf + (size_t)(t & 1) * 16384
                         + (size_t)arow * 256 + lq * 2;
        const unsigned p32 = pat32(t);
        const u64 P64 = ((u64)p32 << 32) | p32;

        // ---- poll+load the A-fragments (this IS the inter-wave sync) ----
        u64 A2[32][2];
        #pragma unroll
        for (int kc = 0; kc < 32; ++kc) {
            A2[kc][0] = __hip_atomic_load(cur + kc * 8,     __ATOMIC_RELAXED, __HIP_MEMORY_SCOPE_AGENT);
            A2[kc][1] = __hip_atomic_load(cur + kc * 8 + 1, __ATOMIC_RELAXED, __HIP_MEMORY_SCOPE_AGENT);
        }
        unsigned fm = 0u;
        #pragma unroll
        for (int kc = 0; kc < 32; ++kc) {
            const u64 y = ((A2[kc][0] ^ P64) | (A2[kc][1] ^ P64)) & SIGN64;
            fm |= (y != 0ull) ? (1u << kc) : 0u;
        }
        while (__ballot(fm != 0u) != 0ull) {
            #pragma unroll
            for (int kc = 0; kc < 32; ++kc) {
                if (fm & (1u << kc)) {
                    A2[kc][0] = __hip_atomic_load(cur + kc * 8,     __ATOMIC_RELAXED, __HIP_MEMORY_SCOPE_AGENT);
                    A2[kc][1] = __hip_atomic_load(cur + kc * 8 + 1, __ATOMIC_RELAXED, __HIP_MEMORY_SCOPE_AGENT);
                }
            }
            #pragma unroll
            for (int kc = 0; kc < 32; ++kc) {
                if (fm & (1u << kc)) {
                    const u64 y = ((A2[kc][0] ^ P64) | (A2[kc][1] ^ P64)) & SIGN64;
                    if (y == 0ull) fm &= ~(1u << kc);
                }
            }
        }

        // ---- strip tags, MFMA over K=1024 (4 independent acc chains) ----
        f32x4 acc[4] = {{0,0,0,0},{0,0,0,0},{0,0,0,0},{0,0,0,0}};
        #pragma unroll
        for (int kc = 0; kc < 32; ++kc) {
            union { u64 d[2]; s16x8 s; } u;
            u.d[0] = A2[kc][0] & STRIP64;
            u.d[1] = A2[kc][1] & STRIP64;
            acc[kc & 3] = __builtin_amdgcn_mfma_f32_16x16x32_bf16(u.s, wfr[kc], acc[kc & 3], 0, 0, 0);
        }

        // ---- epilogue: rows lq*4+r, col icol ----
        const float phs = PH_SCALE * phv;
        const float pis = PI_SCALE * piv;
        float xn_[4], hv_[4];
        #pragma unroll
        for (int r = 0; r < 4; ++r) {
            const float rec = acc[0][r] + acc[1][r] + acc[2][r] + acc[3][r];
            float drive = 0.f;
            if (isStr) drive = (ipf[r].x + pis) * iw0 + (ipf[r].y + pis) * iw1 +
                               (ipf[r].z + pis) * iw2 + (ipf[r].w + pis) * iw3;
            const float xp = xr[r];
            const float xn = xp + DT_ * (-xp + rec + drive + inh[r]) + phs;
            const float hv = fmaxf(xn, 0.f);
            xr[r] = xn; xn_[r] = xn; hv_[r] = hv;
        }

        // ---- publish h[t+1] (skip at t=TT-1: unused, and would alias next replay's t=0 tag) ----
        if (t + 1 < TT) {
            unsigned* nxt = hbuf + (size_t)((t + 1) & 1) * 32768;
            const unsigned pn = pat32(t + 1);
            float prr[4];
            #pragma unroll
            for (int r = 0; r < 4; ++r) prr[r] = __shfl_xor(hv_[r], 1);
            if (!(l15 & 1)) {
                #pragma unroll
                for (int r = 0; r < 4; ++r) {
                    const unsigned val = (((unsigned)bf16_bits(hv_[r]) |
                                           ((unsigned)bf16_bits(prr[r]) << 16)) & 0x7fff7fffu);
                    __hip_atomic_store(nxt + (size_t)(g16 + lq * 4 + r) * 512 + (icol >> 1),
                                       val | pn, __ATOMIC_RELAXED, __HIP_MEMORY_SCOPE_AGENT);
                }
            }
        }

        // ---- off-critical-path: history stores + next-step input prefetch ----
        #pragma unroll
        for (int r = 0; r < 4; ++r) {
            const int bi = g16 + lq * 4 + r;
            const size_t o = ((size_t)bi * TT + t) * HH2 + icol;
            __builtin_nontemporal_store(hv_[r], rnn_out + o);
            __builtin_nontemporal_store(xn_[r], x_out + o);
        }
        const int tn = (t + 1 < TT) ? (t + 1) : t;
        #pragma unroll
        for (int r = 0; r < 4; ++r)
            ipf[r] = *(const float4*)(inp + ((size_t)(g16 + lq * 4 + r) * TT + tn) * 4);
        phv = ph[tn]; piv = pig[tn];
    }
}

// ---------------- fc1: out[b,t] = dot(rnn_out[b,t,512:1024], fc1_w[512:1024]) + fc1_b ----------------
__global__ __launch_bounds__(256) void fc1_kernel(
    const float* __restrict__ rnn_out, const float* __restrict__ fc1_w,
    const float* __restrict__ fc1_b, float* __restrict__ out)
{
    const int wid = blockIdx.x * 4 + (threadIdx.x >> 6);  // [0, 64000)
    const int lane = threadIdx.x & 63;
    const float* p = rnn_out + (size_t)wid * HH2 + HH + lane * 8;
    const float* w = fc1_w + HH + lane * 8;
    f32x4 v0 = *(const f32x4*)(p);
    f32x4 v1 = *(const f32x4*)(p + 4);
    f32x4 w0 = *(const f32x4*)(w);
    f32x4 w1 = *(const f32x4*)(w + 4);
    float s = v0[0]*w0[0] + v0[1]*w0[1] + v0[2]*w0[2] + v0[3]*w0[3]
            + v1[0]*w1[0] + v1[1]*w1[1] + v1[2]*w1[2] + v1[3]*w1[3];
    #pragma unroll
    for (int off = 32; off; off >>= 1) s += __shfl_xor(s, off);
    if (lane == 0) out[wid] = s + fc1_b[0];
}

// ---------------- last-state extraction ----------------
__global__ __launch_bounds__(256) void last_kernel(
    const float* __restrict__ rnn_out, const float* __restrict__ x_out,
    float* __restrict__ hn_last, float* __restrict__ x_last)
{
    const int idx = blockIdx.x * 256 + threadIdx.x;  // [0, 65536)
    const int b = idx >> 10;
    const int i = idx & 1023;
    const size_t o = ((size_t)b * TT + (TT - 1)) * HH2 + i;
    hn_last[idx] = rnn_out[o];
    x_last[idx]  = x_out[o];
}

extern "C" void kernel_launch(void* const* d_in, const int* in_sizes, int n_in,
                              void* d_out, int out_size, void* d_ws, size_t ws_size,
                              hipStream_t stream) {
    const float* inp   = (const float*)d_in[0];   // [64,1000,4]
    const float* hn    = (const float*)d_in[1];   // [1,64,1024]
    const float* x     = (const float*)d_in[2];   // [1,64,1024]
    const float* inhib = (const float*)d_in[3];   // [64,1024]
    const float* ph    = (const float*)d_in[4];   // [1000]
    const float* pi    = (const float*)d_in[5];   // [1000]
    const float* s2s   = (const float*)d_in[6];   // [512,512]
    const float* a2a   = (const float*)d_in[7];
    const float* a2s   = (const float*)d_in[8];
    const float* s2a   = (const float*)d_in[9];
    const float* iw    = (const float*)d_in[10];  // [4,1024]
    const float* fw    = (const float*)d_in[11];  // [1,1024]
    const float* fb    = (const float*)d_in[12];  // [1]

    // Output tuple layout (floats): out | hn_last | rnn_out | x_last | x_out
    float* out     = (float*)d_out;               // 64000
    float* hn_last = out + 64000;                 // 65536
    float* rnn_out = out + 129536;                // 65,536,000
    float* x_last  = out + 65665536;              // 65536
    float* x_out   = out + 65731072;              // 65,536,000

    // Workspace: hbuf [2][64][512] u32 = 256 KB. No init needed: generation tags
    // self-disambiguate against both 0xAA poison and previous-replay residue.
    unsigned* hbuf = (unsigned*)d_ws;

    rnn_persistent<<<256, 64, 0, stream>>>(inp, hn, x, inhib, ph, pi,
                                           s2s, a2a, a2s, s2a, iw,
                                           rnn_out, x_out, hbuf);
    fc1_kernel<<<16000, 256, 0, stream>>>(rnn_out, fw, fb, out);
    last_kernel<<<256, 256, 0, stream>>>(rnn_out, x_out, hn_last, x_last);
}

// Round 7
// 4049.119 us; speedup vs baseline: 1.3908x; 1.3908x over previous
//
#include <hip/hip_runtime.h>
#include <hip/hip_bf16.h>

#define TT 1000
#define HH 512
#define HH2 1024
#define DT_ 0.01f
// sqrt(2*DT*SIGMA_RECUR^2), sqrt(2*DT*SIGMA_INPUT^2)
#define PH_SCALE 7.0710678118654745e-4f
#define PI_SCALE 7.0710678118654745e-3f

typedef short s16x8 __attribute__((ext_vector_type(8)));
typedef float f32x4 __attribute__((ext_vector_type(4)));
typedef unsigned long long u64;

#define SIGN64  0x8000800080008000ull
#define STRIP64 0x7fff7fff7fff7fffull

static __device__ __forceinline__ unsigned short bf16_bits(float f) {
    union { __hip_bfloat16 h; unsigned short u; } b; b.h = __float2bfloat16(f); return b.u;
}
// generation tag for h[t]: 2 bits, period 4; same-slot reuse distance 2 -> always
// differs. End-of-run slots hold tag 3, first-run 0xAA poison reads tag 3, while
// t=0/1 expect tag 0 -> stale data can never satisfy a poll. (R6-proven.)
static __device__ __forceinline__ unsigned pat32(int t) {
    const unsigned tg = ((unsigned)t >> 1) & 3u;
    return ((tg & 1u) << 15) | ((tg & 2u) << 30);
}

// Persistent RNN. Grid: 64 blocks x 256 threads (4 waves). Group = 16 blocks
// owning batch rows [16g, 16g+16); block covers 64 cols (4 waves x 16), wave
// computes a 16x16 C tile. h exchange: agent-scope relaxed atomics with
// generation tags embedded in the sign bits of h (h>=0). Publish = 4 relaxed
// stores, fire-and-forget; consumers' cooperative stage loads poll the data
// itself (straggler-only retries), strip tags, and share the tile across the
// block's 4 waves via XOR-swizzled LDS. No barriers-over-memory, no fences, no
// counters, no vmcnt on the critical path. Deadlock-free: a wave only waits on
// data its producers unconditionally publish.
__global__ __launch_bounds__(256, 1) void rnn_persistent(
    const float* __restrict__ inp, const float* __restrict__ hn,
    const float* __restrict__ x0g, const float* __restrict__ inhib,
    const float* __restrict__ ph, const float* __restrict__ pig,
    const float* __restrict__ s2s, const float* __restrict__ a2a,
    const float* __restrict__ a2s, const float* __restrict__ s2a,
    const float* __restrict__ iw,
    float* __restrict__ rnn_out, float* __restrict__ x_out,
    unsigned* __restrict__ hbuf)         // [2][64][512] u32 (packed tagged bf16 pairs)
{
    const int tid  = threadIdx.x;
    const int wid  = tid >> 6;
    const int lane = tid & 63;
    const int b    = blockIdx.x;         // 0..63
    const int g    = b >> 4;             // row group (batch rows 16g..16g+16)
    const int qb   = b & 15;             // block within group
    const int nt   = qb * 4 + wid;       // column tile 0..63
    const int l15  = lane & 15;
    const int lq   = lane >> 4;
    const int g16  = g * 16;
    const int icol = nt * 16 + l15;      // output column (= W row)

    __shared__ __align__(16) unsigned short hlds[16 * 1024];  // 32 KB swizzled tile

    // ---- publish h0 FIRST (cheap; peers' t=0 polls succeed early) ----
    {
        float h0v[4];
        #pragma unroll
        for (int r = 0; r < 4; ++r)
            h0v[r] = hn[(size_t)(g16 + lq * 4 + r) * HH2 + icol];
        float prr[4];
        #pragma unroll
        for (int r = 0; r < 4; ++r) prr[r] = __shfl_xor(h0v[r], 1);
        if (!(l15 & 1)) {
            const unsigned p0 = pat32(0);
            #pragma unroll
            for (int r = 0; r < 4; ++r) {
                const unsigned val = (((unsigned)bf16_bits(h0v[r]) |
                                       ((unsigned)bf16_bits(prr[r]) << 16)) & 0x7fff7fffu);
                __hip_atomic_store(hbuf + (size_t)(g16 + lq * 4 + r) * 512 + (icol >> 1),
                                   val | p0, __ATOMIC_RELAXED, __HIP_MEMORY_SCOPE_AGENT);
            }
        }
    }

    // ---- W fragments in registers (one-time, f32 -> bf16) ----
    s16x8 wfr[32];
    #pragma unroll
    for (int kc = 0; kc < 32; ++kc) {
        const int j = kc * 32 + lq * 8;
        const float* src;
        if (icol < HH) src = (j < HH) ? (s2s + (size_t)icol * HH + j)
                                      : (a2s + (size_t)icol * HH + (j - HH));
        else           src = (j < HH) ? (s2a + (size_t)(icol - HH) * HH + j)
                                      : (a2a + (size_t)(icol - HH) * HH + (j - HH));
        const float4 f0 = *(const float4*)(src);
        const float4 f1 = *(const float4*)(src + 4);
        union { s16x8 vv; unsigned short us[8]; } u;
        u.us[0] = bf16_bits(f0.x); u.us[1] = bf16_bits(f0.y);
        u.us[2] = bf16_bits(f0.z); u.us[3] = bf16_bits(f0.w);
        u.us[4] = bf16_bits(f1.x); u.us[5] = bf16_bits(f1.y);
        u.us[6] = bf16_bits(f1.z); u.us[7] = bf16_bits(f1.w);
        wfr[kc] = u.vv;
    }

    // ---- register-resident epilogue state (rows lq*4+r of the group tile) ----
    const bool isStr = (icol < HH);
    float iw0 = 0.f, iw1 = 0.f, iw2 = 0.f, iw3 = 0.f;
    if (isStr) {
        iw0 = iw[icol]; iw1 = iw[HH2 + icol];
        iw2 = iw[2 * HH2 + icol]; iw3 = iw[3 * HH2 + icol];
    }
    float xr[4], inh[4];
    float4 ipf[4];
    #pragma unroll
    for (int r = 0; r < 4; ++r) {
        const int bi = g16 + lq * 4 + r;
        xr[r]  = x0g[(size_t)bi * HH2 + icol];
        inh[r] = inhib[(size_t)bi * HH2 + icol];
        ipf[r] = *(const float4*)(inp + ((size_t)bi * TT + 0) * 4);
    }
    float phv = ph[0], piv = pig[0];

    #pragma unroll 1
    for (int t = 0; t < TT; ++t) {
        const u64* src64 = (const u64*)hbuf + (size_t)(t & 1) * 16384;
        const unsigned p32 = pat32(t);
        const u64 P64 = ((u64)p32 << 32) | p32;

        // protect LDS from previous iteration's readers
        __syncthreads();

        // ---- cooperative poll+stage: 8 x 16B chunks per thread ----
        {
            u64 c0[8], c1[8];
            unsigned fm = 0u;
            #pragma unroll
            for (int rd = 0; rd < 8; ++rd) {
                const int gch = tid + rd * 256;            // chunk id [0,2048)
                const int row = gch >> 7, c16 = gch & 127;
                const u64* p = src64 + (size_t)(g16 + row) * 256 + c16 * 2;
                c0[rd] = __hip_atomic_load(p,     __ATOMIC_RELAXED, __HIP_MEMORY_SCOPE_AGENT);
                c1[rd] = __hip_atomic_load(p + 1, __ATOMIC_RELAXED, __HIP_MEMORY_SCOPE_AGENT);
            }
            #pragma unroll
            for (int rd = 0; rd < 8; ++rd)
                if ((((c0[rd] ^ P64) | (c1[rd] ^ P64)) & SIGN64) != 0ull) fm |= 1u << rd;
            while (fm) {
                #pragma unroll
                for (int rd = 0; rd < 8; ++rd) {
                    if (fm & (1u << rd)) {
                        const int gch = tid + rd * 256;
                        const int row = gch >> 7, c16 = gch & 127;
                        const u64* p = src64 + (size_t)(g16 + row) * 256 + c16 * 2;
                        const u64 a = __hip_atomic_load(p,     __ATOMIC_RELAXED, __HIP_MEMORY_SCOPE_AGENT);
                        const u64 c = __hip_atomic_load(p + 1, __ATOMIC_RELAXED, __HIP_MEMORY_SCOPE_AGENT);
                        if ((((a ^ P64) | (c ^ P64)) & SIGN64) == 0ull) {
                            c0[rd] = a; c1[rd] = c; fm &= ~(1u << rd);
                        }
                    }
                }
            }
            #pragma unroll
            for (int rd = 0; rd < 8; ++rd) {
                const int gch = tid + rd * 256;
                const int row = gch >> 7, c16 = gch & 127;
                u64* lp = (u64*)((char*)hlds + row * 2048 + ((c16 ^ (row & 7)) * 16));
                lp[0] = c0[rd] & STRIP64;
                lp[1] = c1[rd] & STRIP64;
            }
        }
        __syncthreads();

        // ---- MFMA: C rows lq*4+r, col icol, K=1024 from swizzled LDS ----
        f32x4 acc0 = {0.f, 0.f, 0.f, 0.f};
        f32x4 acc1 = {0.f, 0.f, 0.f, 0.f};
        const char* arow = (const char*)hlds + l15 * 2048;
        #pragma unroll
        for (int kc = 0; kc < 32; kc += 2) {
            s16x8 a0 = *(const s16x8*)(arow + ((((kc)     << 2 | lq) ^ (l15 & 7)) * 16));
            s16x8 a1 = *(const s16x8*)(arow + ((((kc + 1) << 2 | lq) ^ (l15 & 7)) * 16));
            acc0 = __builtin_amdgcn_mfma_f32_16x16x32_bf16(a0, wfr[kc],     acc0, 0, 0, 0);
            acc1 = __builtin_amdgcn_mfma_f32_16x16x32_bf16(a1, wfr[kc + 1], acc1, 0, 0, 0);
        }

        // ---- epilogue ----
        const float phs = PH_SCALE * phv;
        const float pis = PI_SCALE * piv;
        float xn_[4], hv_[4];
        #pragma unroll
        for (int r = 0; r < 4; ++r) {
            const float rec = acc0[r] + acc1[r];
            float drive = 0.f;
            if (isStr) drive = (ipf[r].x + pis) * iw0 + (ipf[r].y + pis) * iw1 +
                               (ipf[r].z + pis) * iw2 + (ipf[r].w + pis) * iw3;
            const float xp = xr[r];
            const float xn = xp + DT_ * (-xp + rec + drive + inh[r]) + phs;
            const float hv = fmaxf(xn, 0.f);
            xr[r] = xn; xn_[r] = xn; hv_[r] = hv;
        }

        // ---- publish h[t+1], fire-and-forget (skip at t=TT-1: unused; keeps
        //      replay tag-safety: end-state tags never equal t=0/1 expectations) ----
        if (t + 1 < TT) {
            unsigned* nxt = hbuf + (size_t)((t + 1) & 1) * 32768;
            const unsigned pn = pat32(t + 1);
            float prr[4];
            #pragma unroll
            for (int r = 0; r < 4; ++r) prr[r] = __shfl_xor(hv_[r], 1);
            if (!(l15 & 1)) {
                #pragma unroll
                for (int r = 0; r < 4; ++r) {
                    const unsigned val = (((unsigned)bf16_bits(hv_[r]) |
                                           ((unsigned)bf16_bits(prr[r]) << 16)) & 0x7fff7fffu);
                    __hip_atomic_store(nxt + (size_t)(g16 + lq * 4 + r) * 512 + (icol >> 1),
                                       val | pn, __ATOMIC_RELAXED, __HIP_MEMORY_SCOPE_AGENT);
                }
            }
        }

        // ---- off-critical-path: history stores + next-step input prefetch ----
        #pragma unroll
        for (int r = 0; r < 4; ++r) {
            const int bi = g16 + lq * 4 + r;
            const size_t o = ((size_t)bi * TT + t) * HH2 + icol;
            __builtin_nontemporal_store(hv_[r], rnn_out + o);
            __builtin_nontemporal_store(xn_[r], x_out + o);
        }
        const int tn = (t + 1 < TT) ? (t + 1) : t;
        #pragma unroll
        for (int r = 0; r < 4; ++r)
            ipf[r] = *(const float4*)(inp + ((size_t)(g16 + lq * 4 + r) * TT + tn) * 4);
        phv = ph[tn]; piv = pig[tn];
    }
}

// ---------------- fc1: out[b,t] = dot(rnn_out[b,t,512:1024], fc1_w[512:1024]) + fc1_b ----------------
__global__ __launch_bounds__(256) void fc1_kernel(
    const float* __restrict__ rnn_out, const float* __restrict__ fc1_w,
    const float* __restrict__ fc1_b, float* __restrict__ out)
{
    const int wid = blockIdx.x * 4 + (threadIdx.x >> 6);  // [0, 64000)
    const int lane = threadIdx.x & 63;
    const float* p = rnn_out + (size_t)wid * HH2 + HH + lane * 8;
    const float* w = fc1_w + HH + lane * 8;
    f32x4 v0 = *(const f32x4*)(p);
    f32x4 v1 = *(const f32x4*)(p + 4);
    f32x4 w0 = *(const f32x4*)(w);
    f32x4 w1 = *(const f32x4*)(w + 4);
    float s = v0[0]*w0[0] + v0[1]*w0[1] + v0[2]*w0[2] + v0[3]*w0[3]
            + v1[0]*w1[0] + v1[1]*w1[1] + v1[2]*w1[2] + v1[3]*w1[3];
    #pragma unroll
    for (int off = 32; off; off >>= 1) s += __shfl_xor(s, off);
    if (lane == 0) out[wid] = s + fc1_b[0];
}

// ---------------- last-state extraction ----------------
__global__ __launch_bounds__(256) void last_kernel(
    const float* __restrict__ rnn_out, const float* __restrict__ x_out,
    float* __restrict__ hn_last, float* __restrict__ x_last)
{
    const int idx = blockIdx.x * 256 + threadIdx.x;  // [0, 65536)
    const int b = idx >> 10;
    const int i = idx & 1023;
    const size_t o = ((size_t)b * TT + (TT - 1)) * HH2 + i;
    hn_last[idx] = rnn_out[o];
    x_last[idx]  = x_out[o];
}

extern "C" void kernel_launch(void* const* d_in, const int* in_sizes, int n_in,
                              void* d_out, int out_size, void* d_ws, size_t ws_size,
                              hipStream_t stream) {
    const float* inp   = (const float*)d_in[0];   // [64,1000,4]
    const float* hn    = (const float*)d_in[1];   // [1,64,1024]
    const float* x     = (const float*)d_in[2];   // [1,64,1024]
    const float* inhib = (const float*)d_in[3];   // [64,1024]
    const float* ph    = (const float*)d_in[4];   // [1000]
    const float* pi    = (const float*)d_in[5];   // [1000]
    const float* s2s   = (const float*)d_in[6];   // [512,512]
    const float* a2a   = (const float*)d_in[7];
    const float* a2s   = (const float*)d_in[8];
    const float* s2a   = (const float*)d_in[9];
    const float* iw    = (const float*)d_in[10];  // [4,1024]
    const float* fw    = (const float*)d_in[11];  // [1,1024]
    const float* fb    = (const float*)d_in[12];  // [1]

    // Output tuple layout (floats): out | hn_last | rnn_out | x_last | x_out
    float* out     = (float*)d_out;               // 64000
    float* hn_last = out + 64000;                 // 65536
    float* rnn_out = out + 129536;                // 65,536,000
    float* x_last  = out + 65665536;              // 65536
    float* x_out   = out + 65731072;              // 65,536,000

    // Workspace: hbuf [2][64][512] u32 = 256 KB. No init needed: generation tags
    // self-disambiguate against both 0xAA poison and previous-replay residue.
    unsigned* hbuf = (unsigned*)d_ws;

    rnn_persistent<<<64, 256, 0, stream>>>(inp, hn, x, inhib, ph, pi,
                                           s2s, a2a, a2s, s2a, iw,
                                           rnn_out, x_out, hbuf);
    fc1_kernel<<<16000, 256, 0, stream>>>(rnn_out, fw, fb, out);
    last_kernel<<<256, 256, 0, stream>>>(rnn_out, x_out, hn_last, x_last);
}